// Round 3
// baseline (150.856 us; speedup 1.0000x reference)
//
#include <hip/hip_runtime.h>
#include <float.h>

#define B_ 16
#define D_ 64
#define L_ 8192
#define K_ 512
#define NBLOCKS 256
#define TILES_PER_BLOCK 8     // 2048 tiles / 256 blocks
#define EPS 0.0625f

typedef __attribute__((ext_vector_type(8))) short short8;
typedef __attribute__((ext_vector_type(4))) float f32x4;

__device__ __forceinline__ unsigned short bf16_rne(float x) {
    unsigned u = __float_as_uint(x);
    return (unsigned short)((u + 0x7fffu + ((u >> 16) & 1u)) >> 16);
}

// Bit-exact numpy-semantics score: sequential-d FMA dot (sgemm order),
// then (xs - 2*dot) + es. E column prefetched 16-wide to avoid a chained
// 64 x global-load latency stall. Rare path (~1% of tokens).
__device__ __attribute__((noinline))
float exact_score(const float* __restrict__ E, const float (*xT)[65],
                  int token, int code, float xs, float es) {
    float dot = 0.f;
    #pragma unroll 1
    for (int d0 = 0; d0 < 64; d0 += 16) {
        float ev[16], xv[16];
        #pragma unroll
        for (int m = 0; m < 16; ++m) ev[m] = E[(d0 + m) * K_ + code];
        #pragma unroll
        for (int m = 0; m < 16; ++m) xv[m] = xT[d0 + m][token];
        #pragma unroll
        for (int m = 0; m < 16; ++m) dot = fmaf(xv[m], ev[m], dot);
    }
    return (xs - 2.0f * dot) + es;
}

// 512 threads = 8 waves. Wave w: codes w*64..w*64+63 (4 MFMA col-blocks,
// B-frags resident in VGPRs), all 64 tokens of the tile (4 row-blocks).
// C-frag layout (m89-verified): col=lane&15, row=(lane>>4)*4+reg.
__global__ __launch_bounds__(512, 2)
void vq_mfma_kernel(const float* __restrict__ X, const float* __restrict__ E,
                    float* __restrict__ out_emb, float* __restrict__ out_idx)
{
    __shared__ __align__(16) short xAhi[4096];   // [tb][s][lane] 8 bf16, frag-linear
    __shared__ __align__(16) short xAlo[4096];
    __shared__ float xT[64][65];                 // fp32 x, [d][token] (+1 pad)
    __shared__ float esq_s[K_];
    __shared__ float xsq_s[64];
    __shared__ float thr_s[64];
    __shared__ float redv[8][64];
    __shared__ unsigned redc[8][64];
    __shared__ unsigned redk[8][64];
    __shared__ unsigned long long red64[8][64];
    __shared__ int bestk_s[64];
    __shared__ int needx_s[64];
    __shared__ int needB_s;

    const int tid  = threadIdx.x;
    const int lane = tid & 63;
    const int wave = tid >> 6;
    const int lo4  = lane & 15;
    const int hi4  = lane >> 4;

    // ---------------- init: esq (np sequential axis-0, round-then-add) ----
    {
        float s = 0.f;
        #pragma unroll 1
        for (int d = 0; d < D_; ++d) {
            float v = E[d * K_ + tid];
            float sq = v * v;
            asm volatile("" : "+v"(sq));   // block mul+add fusion (np rounds square)
            s = s + sq;
        }
        esq_s[tid] = s;
    }

    // ---------------- init: resident B-frags (codebook hi/lo bf16) --------
    // frag map: lane l -> B[k=(l>>4)*8+j][col=l&15]; k-map permutation cancels
    // between A and B operands.
    short8 Bhi[4][2], Blo[4][2];
    #pragma unroll
    for (int q = 0; q < 4; ++q) {
        int code = (wave * 4 + q) * 16 + lo4;
        #pragma unroll
        for (int s = 0; s < 2; ++s) {
            short8 h, l;
            #pragma unroll
            for (int j = 0; j < 8; ++j) {
                int d = s * 32 + hi4 * 8 + j;
                float v = E[d * K_ + code];
                unsigned short hb = bf16_rne(v);
                float hf = __uint_as_float((unsigned)hb << 16);
                float lov = v - hf;                    // exact (Sterbenz)
                h[j] = (short)hb;
                l[j] = (short)bf16_rne(lov);
            }
            Bhi[q][s] = h;
            Blo[q][s] = l;
        }
    }

    for (int t = 0; t < TILES_PER_BLOCK; ++t) {
        int tile = blockIdx.x * TILES_PER_BLOCK + t;
        int b  = tile >> 7;
        int l0 = (tile & 127) << 6;

        __syncthreads();                                         // (1)

        // ---- stage x: coalesced global reads; write fp32 xT + bf16 A-frags
        {
            const float* xb = X + ((size_t)(b * 64 + wave * 8)) * L_ + l0 + lane;
            float xv[8];
            #pragma unroll
            for (int r = 0; r < 8; ++r) xv[r] = xb[(size_t)r * L_];
            #pragma unroll
            for (int r = 0; r < 8; ++r) xT[wave * 8 + r][lane] = xv[r];
            short8 h8, l8;
            #pragma unroll
            for (int r = 0; r < 8; ++r) {
                unsigned short hb = bf16_rne(xv[r]);
                float hf = __uint_as_float((unsigned)hb << 16);
                h8[r] = (short)hb;
                l8[r] = (short)bf16_rne(xv[r] - hf);
            }
            int s  = wave >> 2, g = wave & 3;
            int tb = lane >> 4, row = lane & 15;
            int unit = (tb * 2 + s) * 64 + g * 16 + row;
            ((short8*)xAhi)[unit] = h8;
            ((short8*)xAlo)[unit] = l8;
        }
        __syncthreads();                                         // (2)

        // ---- xsq (np pairwise-8, rounded squares) by wave 0 --------------
        if (tid < 64) {
            float r8[8];
            #pragma unroll
            for (int j = 0; j < 8; ++j) {
                float v = xT[j][tid];
                float sq = v * v;
                asm volatile("" : "+v"(sq));
                r8[j] = sq;
            }
            #pragma unroll
            for (int m = 1; m < 8; ++m)
                #pragma unroll
                for (int j = 0; j < 8; ++j) {
                    float v = xT[m * 8 + j][tid];
                    float sq = v * v;
                    asm volatile("" : "+v"(sq));
                    r8[j] = r8[j] + sq;
                }
            xsq_s[tid] = ((r8[0] + r8[1]) + (r8[2] + r8[3])) +
                         ((r8[4] + r8[5]) + (r8[6] + r8[7]));
        }

        // ---- MFMA: 4 row-blocks x 4 col-blocks x 6 (K=192 hi/lo stack) ---
        f32x4 acc[4][4];
        #pragma unroll
        for (int tb = 0; tb < 4; ++tb) {
            short8 ah0 = ((const short8*)xAhi)[(tb * 2 + 0) * 64 + lane];
            short8 ah1 = ((const short8*)xAhi)[(tb * 2 + 1) * 64 + lane];
            short8 al0 = ((const short8*)xAlo)[(tb * 2 + 0) * 64 + lane];
            short8 al1 = ((const short8*)xAlo)[(tb * 2 + 1) * 64 + lane];
            #pragma unroll
            for (int q = 0; q < 4; ++q) {
                f32x4 c = {0.f, 0.f, 0.f, 0.f};
                c = __builtin_amdgcn_mfma_f32_16x16x32_bf16(ah0, Bhi[q][0], c, 0, 0, 0);
                c = __builtin_amdgcn_mfma_f32_16x16x32_bf16(ah1, Bhi[q][1], c, 0, 0, 0);
                c = __builtin_amdgcn_mfma_f32_16x16x32_bf16(ah0, Blo[q][0], c, 0, 0, 0);
                c = __builtin_amdgcn_mfma_f32_16x16x32_bf16(ah1, Blo[q][1], c, 0, 0, 0);
                c = __builtin_amdgcn_mfma_f32_16x16x32_bf16(al0, Bhi[q][0], c, 0, 0, 0);
                c = __builtin_amdgcn_mfma_f32_16x16x32_bf16(al1, Bhi[q][1], c, 0, 0, 0);
                acc[tb][q] = c;
            }
        }
        __syncthreads();                                         // (3) xsq ready

        // ---- transform to scores (in place) + per-token min --------------
        float xs_r[4][4];
        #pragma unroll
        for (int tb = 0; tb < 4; ++tb)
            #pragma unroll
            for (int r = 0; r < 4; ++r)
                xs_r[tb][r] = xsq_s[tb * 16 + hi4 * 4 + r];
        float es_q[4];
        #pragma unroll
        for (int q = 0; q < 4; ++q) es_q[q] = esq_s[(wave * 4 + q) * 16 + lo4];

        float mloc[4][4];
        #pragma unroll
        for (int tb = 0; tb < 4; ++tb)
            #pragma unroll
            for (int r = 0; r < 4; ++r) {
                float m = FLT_MAX;
                #pragma unroll
                for (int q = 0; q < 4; ++q) {
                    float sc = (xs_r[tb][r] - 2.0f * acc[tb][q][r]) + es_q[q];
                    acc[tb][q][r] = sc;
                    m = fminf(m, sc);
                }
                mloc[tb][r] = m;
            }
        #pragma unroll
        for (int off = 1; off < 16; off <<= 1)
            #pragma unroll
            for (int tb = 0; tb < 4; ++tb)
                #pragma unroll
                for (int r = 0; r < 4; ++r)
                    mloc[tb][r] = fminf(mloc[tb][r], __shfl_xor(mloc[tb][r], off, 64));
        if (lo4 == 0)
            #pragma unroll
            for (int tb = 0; tb < 4; ++tb)
                #pragma unroll
                for (int r = 0; r < 4; ++r)
                    redv[wave][tb * 16 + hi4 * 4 + r] = mloc[tb][r];
        __syncthreads();                                         // (4)

        if (tid < 64) {
            float m = redv[0][tid];
            #pragma unroll
            for (int w = 1; w < 8; ++w) m = fminf(m, redv[w][tid]);
            thr_s[tid] = m + EPS;
        }
        __syncthreads();                                         // (5)

        // ---- candidate count + k-of-candidate-min ------------------------
        float th_r[4][4];
        #pragma unroll
        for (int tb = 0; tb < 4; ++tb)
            #pragma unroll
            for (int r = 0; r < 4; ++r)
                th_r[tb][r] = thr_s[tb * 16 + hi4 * 4 + r];

        unsigned cnt[4][4], km[4][4];
        #pragma unroll
        for (int tb = 0; tb < 4; ++tb)
            #pragma unroll
            for (int r = 0; r < 4; ++r) { cnt[tb][r] = 0u; km[tb][r] = 0xFFFFFFFFu; }
        #pragma unroll
        for (int tb = 0; tb < 4; ++tb)
            #pragma unroll
            for (int q = 0; q < 4; ++q) {
                unsigned code = (unsigned)((wave * 4 + q) * 16 + lo4);
                #pragma unroll
                for (int r = 0; r < 4; ++r) {
                    if (acc[tb][q][r] <= th_r[tb][r]) {
                        cnt[tb][r] += 1u;
                        if (code < km[tb][r]) km[tb][r] = code;
                    }
                }
            }
        #pragma unroll
        for (int off = 1; off < 16; off <<= 1)
            #pragma unroll
            for (int tb = 0; tb < 4; ++tb)
                #pragma unroll
                for (int r = 0; r < 4; ++r) {
                    cnt[tb][r] += __shfl_xor(cnt[tb][r], off, 64);
                    unsigned ok = __shfl_xor(km[tb][r], off, 64);
                    if (ok < km[tb][r]) km[tb][r] = ok;
                }
        if (lo4 == 0)
            #pragma unroll
            for (int tb = 0; tb < 4; ++tb)
                #pragma unroll
                for (int r = 0; r < 4; ++r) {
                    int token = tb * 16 + hi4 * 4 + r;
                    redc[wave][token] = cnt[tb][r];
                    redk[wave][token] = km[tb][r];
                }
        __syncthreads();                                         // (6)

        if (tid < 64) {
            unsigned c = 0u, k = 0xFFFFFFFFu;
            #pragma unroll
            for (int w = 0; w < 8; ++w) {
                c += redc[w][tid];
                unsigned ok = redk[w][tid];
                if (ok < k) k = ok;
            }
            int nx = (c >= 2u) ? 1 : 0;
            needx_s[tid] = nx;
            if (!nx) bestk_s[tid] = (int)k;    // unique candidate == np argmin
            unsigned long long bal = __ballot(nx != 0);
            if (tid == 0) needB_s = (bal != 0ULL) ? 1 : 0;
        }
        __syncthreads();                                         // (7)

        // ---- rare exact pass: >=2 near-ties -> bit-exact numpy recompute -
        if (needB_s) {
            int nx_r[4][4];
            #pragma unroll
            for (int tb = 0; tb < 4; ++tb)
                #pragma unroll
                for (int r = 0; r < 4; ++r)
                    nx_r[tb][r] = needx_s[tb * 16 + hi4 * 4 + r];
            unsigned long long pv[4][4];
            #pragma unroll
            for (int tb = 0; tb < 4; ++tb)
                #pragma unroll
                for (int r = 0; r < 4; ++r) pv[tb][r] = ~0ULL;
            #pragma unroll
            for (int tb = 0; tb < 4; ++tb)
                #pragma unroll
                for (int q = 0; q < 4; ++q) {
                    int code = (wave * 4 + q) * 16 + lo4;
                    #pragma unroll
                    for (int r = 0; r < 4; ++r) {
                        if (nx_r[tb][r] && acc[tb][q][r] <= th_r[tb][r]) {
                            int token = tb * 16 + hi4 * 4 + r;
                            float ex = exact_score(E, xT, token, code,
                                                   xs_r[tb][r], es_q[q]);
                            unsigned long long pk =
                                ((unsigned long long)__float_as_uint(ex) << 32) |
                                (unsigned)code;
                            if (pk < pv[tb][r]) pv[tb][r] = pk;
                        }
                    }
                }
            #pragma unroll
            for (int off = 1; off < 16; off <<= 1)
                #pragma unroll
                for (int tb = 0; tb < 4; ++tb)
                    #pragma unroll
                    for (int r = 0; r < 4; ++r) {
                        unsigned long long o = __shfl_xor(pv[tb][r], off, 64);
                        if (o < pv[tb][r]) pv[tb][r] = o;
                    }
            if (lo4 == 0)
                #pragma unroll
                for (int tb = 0; tb < 4; ++tb)
                    #pragma unroll
                    for (int r = 0; r < 4; ++r)
                        red64[wave][tb * 16 + hi4 * 4 + r] = pv[tb][r];
            __syncthreads();                                     // (8)
            if (tid < 64 && needx_s[tid]) {
                unsigned long long m = ~0ULL;
                #pragma unroll
                for (int w = 0; w < 8; ++w) {
                    unsigned long long o = red64[w][tid];
                    if (o < m) m = o;
                }
                bestk_s[tid] = (int)(unsigned)(m & 0xFFFFFFFFULL);
            }
            __syncthreads();                                     // (9)
        }

        // ---- epilogue: gather exact fp32 codebook rows + write ----------
        {
            int qd = tid & 15, dg = tid >> 4;
            int i4 = qd * 4;
            int k0 = bestk_s[i4], k1 = bestk_s[i4 + 1];
            int k2 = bestk_s[i4 + 2], k3 = bestk_s[i4 + 3];
            #pragma unroll
            for (int h = 0; h < 2; ++h) {
                int d = dg + h * 32;
                float4 v;
                v.x = E[d * K_ + k0]; v.y = E[d * K_ + k1];
                v.z = E[d * K_ + k2]; v.w = E[d * K_ + k3];
                *reinterpret_cast<float4*>(out_emb + ((size_t)(b * 64 + d)) * L_ + l0 + i4) = v;
            }
        }
        if (tid < 64)
            out_idx[(size_t)b * L_ + l0 + tid] = (float)bestk_s[tid];
    }
}

extern "C" void kernel_launch(void* const* d_in, const int* in_sizes, int n_in,
                              void* d_out, int out_size, void* d_ws, size_t ws_size,
                              hipStream_t stream) {
    const float* X = (const float*)d_in[0];   // (B, D, L) fp32
    const float* E = (const float*)d_in[1];   // (D, K) fp32
    float* out     = (float*)d_out;
    float* out_emb = out;
    float* out_idx = out + (size_t)B_ * D_ * L_;
    vq_mfma_kernel<<<NBLOCKS, 512, 0, stream>>>(X, E, out_emb, out_idx);
}